// Round 9
// baseline (246.560 us; speedup 1.0000x reference)
//
#include <hip/hip_runtime.h>
#include <math.h>

// Problem: lkd scan over T=65536 steps, DIM=512, fp32. Closed form:
//   D_t = v + c*t ; mu_t = ((v-c)mu0 + c Z_t)/D_{t-1} ; Z_t excl. prefix of z.
//   Per-chunk moments: S0=sum r, S1=sum r*w, S2=sum r*w^2 with
//   r=1/(D_t D_{t-1}), w = Dprev*z - k0 - c*L (L = excl. local prefix), so
//   chunk quad = kq*(S2 - 2cP*S1 + (cP)^2*S0), P = inter-chunk excl. prefix.
//
// R4: NON-cooperative 2-kernel pipeline (R3's hipLaunchCooperativeKernel
// killed the container twice — suspected grid.sync deadlock under graph
// capture; abandoned). Scan kernels eliminated instead: each combine block
// computes its own flat prefix P directly from the 2 MB L2-resident sums
// array (<=1008 coalesced loads/thread). fp64 logdet lives in K2 block 0
// so its register pressure never touches the streaming kernel.
// Pipeline: memset(4B) -> K1 moments -> K2 prefix+combine+logdet.
// Workspace: 4*CHUNKS*DIM floats = 8 MB.

#define DIM    512
#define TT     65536
#define CHUNKS 1024
#define ROWS   64      // TT / CHUNKS
#define GROUPS 64
#define CPG    16      // CHUNKS / GROUPS

#define TWO_PI 6.283185307179586

// K1: fused colsum + moment pass. grid=CHUNKS, block=128 (4 cols/thread, float4).
// Identical to the measured-good R2 kernel (207 us pipeline).
__global__ __launch_bounds__(128) void k1_fused(const float* __restrict__ z,
                                                const float* __restrict__ var_vbl,
                                                const float* __restrict__ corr_vbl,
                                                const float* __restrict__ prior_mu,
                                                float* __restrict__ sums,
                                                float* __restrict__ s0a,
                                                float* __restrict__ s1a,
                                                float* __restrict__ s2a) {
    const int chunk = blockIdx.x;
    const int tid = threadIdx.x;  // 0..127
    const int d0 = tid * 4;
    const float t0m1 = (float)(chunk * ROWS) - 1.0f;

    float vv[4], cc[4], k0[4], L[4], S0[4], S1[4], S2[4], Dprev[4], invDprev[4];
#pragma unroll
    for (int j = 0; j < 4; ++j) {
        const int d = d0 + j;
        float spv = log1pf(expf(var_vbl[d]));
        float v = spv * spv;
        float c = v / (1.0f + expf(-corr_vbl[d]));
        vv[j] = v;
        cc[j] = c;
        k0[j] = (v - c) * prior_mu[d];      // (v-c)*mu0
        L[j] = 0.f; S0[j] = 0.f; S1[j] = 0.f; S2[j] = 0.f;
        Dprev[j] = fmaf(c, t0m1, v);        // D_{t0-1}
        invDprev[j] = __builtin_amdgcn_rcpf(Dprev[j]);
    }

    const float4* zp = reinterpret_cast<const float4*>(z)
                       + (size_t)chunk * ROWS * (DIM / 4) + tid;
    float tf = t0m1 + 1.0f;
#pragma unroll 4
    for (int r = 0; r < ROWS; ++r) {
        float4 zv = zp[(size_t)r * (DIM / 4)];
        float zz[4] = {zv.x, zv.y, zv.z, zv.w};
#pragma unroll
        for (int j = 0; j < 4; ++j) {
            float Dt = fmaf(cc[j], tf, vv[j]);             // v + c*t
            float invDt = __builtin_amdgcn_rcpf(Dt);
            float w = fmaf(Dprev[j], zz[j], -fmaf(cc[j], L[j], k0[j]));
            float rr = invDt * invDprev[j];
            S0[j] += rr;
            float rw = rr * w;
            S1[j] += rw;
            S2[j] = fmaf(rw, w, S2[j]);
            L[j] += zz[j];
            Dprev[j] = Dt;
            invDprev[j] = invDt;
        }
        tf += 1.0f;
    }

    const size_t o4 = (size_t)chunk * (DIM / 4) + tid;
    reinterpret_cast<float4*>(sums)[o4] = make_float4(L[0], L[1], L[2], L[3]);
    reinterpret_cast<float4*>(s0a)[o4] = make_float4(S0[0], S0[1], S0[2], S0[3]);
    reinterpret_cast<float4*>(s1a)[o4] = make_float4(S1[0], S1[1], S1[2], S1[3]);
    reinterpret_cast<float4*>(s2a)[o4] = make_float4(S2[0], S2[1], S2[2], S2[3]);
}

// K2: per-group flat prefix + moment combine + (block 0) fp64 logdet.
// grid=GROUPS, block=512. out must be pre-zeroed (memset).
__global__ __launch_bounds__(512) void k2_combine(const float* __restrict__ sums,
                                                  const float* __restrict__ s0a,
                                                  const float* __restrict__ s1a,
                                                  const float* __restrict__ s2a,
                                                  const float* __restrict__ var_vbl,
                                                  const float* __restrict__ corr_vbl,
                                                  float* __restrict__ out) {
    const int g = blockIdx.x;
    const int d = threadIdx.x;
    float spv = log1pf(expf(var_vbl[d]));
    float v = spv * spv;
    float c = v / (1.0f + expf(-corr_vbl[d]));
    float kq = 0.5f / (v - c);

    // Flat chunk-exclusive prefix for this group's first chunk.
    // sums is 2 MB, L2-resident (just written by K1). Coalesced across d.
    float run = 0.f;
    const int nrows = g * CPG;
#pragma unroll 8
    for (int i = 0; i < nrows; ++i)
        run += sums[(size_t)i * DIM + d];

    float q = 0.f;
#pragma unroll
    for (int i = 0; i < CPG; ++i) {
        const size_t idx = (size_t)(g * CPG + i) * DIM + d;
        float s = sums[idx];
        float S0 = s0a[idx];
        float S1 = s1a[idx];
        float S2 = s2a[idx];
        float cP = c * run;
        q += kq * (S2 - 2.f * cP * S1 + cP * cP * S0);
        run += s;
    }

    // block reduce (8 waves), subtract from out
    for (int off = 32; off > 0; off >>= 1) q += __shfl_down(q, off, 64);
    __shared__ float wsred[8];
    const int lane = d & 63, w = d >> 6;
    if (lane == 0) wsred[w] = q;
    __syncthreads();
    if (d == 0) {
        float tot = 0.f;
#pragma unroll
        for (int i = 0; i < 8; ++i) tot += wsred[i];
        atomicAdd(out, -tot);
    }

    // Block 0: analytic logdet (telescoped), fp64, one column per thread.
    if (g == 0) {
        double sp = log1p(exp((double)var_vbl[d]));
        double vd = sp * sp;
        double cd = vd / (1.0 + exp(-(double)corr_vbl[d]));
        double vmc = vd - cd;
        double Dlast = vd + cd * (double)(TT - 1);
        double Ld = -0.5 * ((double)TT * (log(TWO_PI) + log(vmc)) + log(Dlast / vmc));
        __shared__ double redd[512];
        redd[d] = Ld;
        __syncthreads();
        for (int s = 256; s > 0; s >>= 1) {
            if (d < s) redd[d] += redd[d + s];
            __syncthreads();
        }
        if (d == 0) atomicAdd(out, (float)redd[0]);
    }
}

extern "C" void kernel_launch(void* const* d_in, const int* in_sizes, int n_in,
                              void* d_out, int out_size, void* d_ws, size_t ws_size,
                              hipStream_t stream) {
    const float* z = (const float*)d_in[0];
    const float* var_vbl = (const float*)d_in[1];
    const float* corr_vbl = (const float*)d_in[2];
    const float* prior_mu = (const float*)d_in[3];
    float* out = (float*)d_out;
    float* sums = (float*)d_ws;                          // CHUNKS*DIM (2 MB)
    float* s0a = sums + (size_t)CHUNKS * DIM;            // 2 MB
    float* s1a = s0a + (size_t)CHUNKS * DIM;             // 2 MB
    float* s2a = s1a + (size_t)CHUNKS * DIM;             // 2 MB

    hipMemsetAsync(d_out, 0, sizeof(float), stream);
    k1_fused<<<CHUNKS, 128, 0, stream>>>(z, var_vbl, corr_vbl, prior_mu,
                                         sums, s0a, s1a, s2a);
    k2_combine<<<GROUPS, 512, 0, stream>>>(sums, s0a, s1a, s2a,
                                           var_vbl, corr_vbl, out);
}

// Round 10
// 209.724 us; speedup vs baseline: 1.1756x; 1.1756x over previous
//
#include <hip/hip_runtime.h>
#include <math.h>

// Problem: lkd scan over T=65536 steps, DIM=512, fp32. Closed form:
//   D_t = v + c*t ; mu_t = ((v-c)mu0 + c Z_t)/D_{t-1} ; Z_t excl. prefix of z.
//   Per-chunk moments: S1=sum r*w, S2=sum r*w^2 with r=1/(D_t D_{t-1}),
//   w = Dprev*z - k0 - c*L (L = excl. local prefix); chunk quadratic =
//   kq*(S2 - 2cP*S1 + (cP)^2*S0), P = inter-chunk excl. prefix.
//   S0 is DATA-INDEPENDENT and telescopes: S0 = (1/D_{t0-1} - 1/D_end)/c
//   -> computed closed-form in K2b; never stored (R4's s0a array deleted).
//
// R5: back to the measured-best R2 hierarchical structure (207us), minus
// R4's flat-prefix mistake (serial dependent-add chain over up to 1008 rows
// paid ~500cy L2 latency per unroll batch -> +40us). Group-exclusive prefix
// here is <=63 loads/thread (one latency batch).
// Pipeline (3 dispatches, no memset):
//   K1 moments -> K2a group sums (+extra block: fp64 logdet, plain-stores out)
//   -> K2b scan+combine+atomicAdd.
// Workspace: 3*CHUNKS*DIM + GROUPS*DIM floats = 6.125 MB.

#define DIM    512
#define TT     65536
#define CHUNKS 1024
#define ROWS   64      // TT / CHUNKS
#define GROUPS 64
#define CPG    16      // CHUNKS / GROUPS

#define TWO_PI 6.283185307179586

// K1: fused colsum + moment pass. grid=CHUNKS, block=128 (4 cols/thread, float4).
__global__ __launch_bounds__(128) void k1_fused(const float* __restrict__ z,
                                                const float* __restrict__ var_vbl,
                                                const float* __restrict__ corr_vbl,
                                                const float* __restrict__ prior_mu,
                                                float* __restrict__ sums,
                                                float* __restrict__ s1a,
                                                float* __restrict__ s2a) {
    const int chunk = blockIdx.x;
    const int tid = threadIdx.x;  // 0..127
    const int d0 = tid * 4;
    const float t0m1 = (float)(chunk * ROWS) - 1.0f;

    float vv[4], cc[4], k0[4], L[4], S1[4], S2[4], Dprev[4], invDprev[4];
#pragma unroll
    for (int j = 0; j < 4; ++j) {
        const int d = d0 + j;
        float spv = log1pf(expf(var_vbl[d]));
        float v = spv * spv;
        float c = v / (1.0f + expf(-corr_vbl[d]));
        vv[j] = v;
        cc[j] = c;
        k0[j] = (v - c) * prior_mu[d];      // (v-c)*mu0
        L[j] = 0.f; S1[j] = 0.f; S2[j] = 0.f;
        Dprev[j] = fmaf(c, t0m1, v);        // D_{t0-1}
        invDprev[j] = __builtin_amdgcn_rcpf(Dprev[j]);
    }

    const float4* zp = reinterpret_cast<const float4*>(z)
                       + (size_t)chunk * ROWS * (DIM / 4) + tid;
    float tf = t0m1 + 1.0f;
#pragma unroll 4
    for (int r = 0; r < ROWS; ++r) {
        float4 zv = zp[(size_t)r * (DIM / 4)];
        float zz[4] = {zv.x, zv.y, zv.z, zv.w};
#pragma unroll
        for (int j = 0; j < 4; ++j) {
            float Dt = fmaf(cc[j], tf, vv[j]);             // v + c*t
            float invDt = __builtin_amdgcn_rcpf(Dt);
            float w = fmaf(Dprev[j], zz[j], -fmaf(cc[j], L[j], k0[j]));
            float rw = (invDt * invDprev[j]) * w;          // r_t * w
            S1[j] += rw;
            S2[j] = fmaf(rw, w, S2[j]);
            L[j] += zz[j];
            Dprev[j] = Dt;
            invDprev[j] = invDt;
        }
        tf += 1.0f;
    }

    const size_t o4 = (size_t)chunk * (DIM / 4) + tid;
    reinterpret_cast<float4*>(sums)[o4] = make_float4(L[0], L[1], L[2], L[3]);
    reinterpret_cast<float4*>(s1a)[o4] = make_float4(S1[0], S1[1], S1[2], S1[3]);
    reinterpret_cast<float4*>(s2a)[o4] = make_float4(S2[0], S2[1], S2[2], S2[3]);
}

// K2a: group totals (blocks 0..63) + fp64 logdet (block 64, plain-stores out).
// grid=GROUPS+1, block=512.
__global__ __launch_bounds__(512) void k2a_gsum(const float* __restrict__ sums,
                                                float* __restrict__ gsums,
                                                const float* __restrict__ var_vbl,
                                                const float* __restrict__ corr_vbl,
                                                float* __restrict__ out) {
    const int g = blockIdx.x;
    const int d = threadIdx.x;
    if (g < GROUPS) {
        float vals[CPG];
#pragma unroll
        for (int i = 0; i < CPG; ++i)
            vals[i] = sums[(size_t)(g * CPG + i) * DIM + d];
        float run = 0.f;
#pragma unroll
        for (int i = 0; i < CPG; ++i) run += vals[i];
        gsums[(size_t)g * DIM + d] = run;
    } else {
        // Analytic: sum_t -0.5*log(2pi var_t) telescopes. fp64 for accuracy.
        double sp = log1p(exp((double)var_vbl[d]));
        double vd = sp * sp;
        double cd = vd / (1.0 + exp(-(double)corr_vbl[d]));
        double vmc = vd - cd;
        double Dlast = vd + cd * (double)(TT - 1);
        double Ld = -0.5 * ((double)TT * (log(TWO_PI) + log(vmc)) + log(Dlast / vmc));
        __shared__ double redd[512];
        redd[d] = Ld;
        __syncthreads();
        for (int s = 256; s > 0; s >>= 1) {
            if (d < s) redd[d] += redd[d + s];
            __syncthreads();
        }
        if (d == 0) out[0] = (float)redd[0];   // plain store inits out
    }
}

// K2b: group-exclusive prefix (<=63 gsums loads) + combine 16 chunks + reduce.
// grid=GROUPS, block=512. Runs after K2a (stream order) so out is initialized.
__global__ __launch_bounds__(512) void k2b_combine(const float* __restrict__ sums,
                                                   const float* __restrict__ s1a,
                                                   const float* __restrict__ s2a,
                                                   const float* __restrict__ gsums,
                                                   const float* __restrict__ var_vbl,
                                                   const float* __restrict__ corr_vbl,
                                                   float* __restrict__ out) {
    const int g = blockIdx.x;
    const int d = threadIdx.x;
    float spv = log1pf(expf(var_vbl[d]));
    float v = spv * spv;
    float c = v / (1.0f + expf(-corr_vbl[d]));
    float kq = 0.5f / (v - c);
    float invc = 1.0f / c;

    // Group-exclusive prefix: <=63 independent loads, one latency batch.
    float run = 0.f;
#pragma unroll 16
    for (int i = 0; i < g; ++i) run += gsums[(size_t)i * DIM + d];

    float q = 0.f;
#pragma unroll
    for (int i = 0; i < CPG; ++i) {
        const int ch = g * CPG + i;
        const size_t idx = (size_t)ch * DIM + d;
        float s = sums[idx];
        float S1 = s1a[idx];
        float S2 = s2a[idx];
        // S0 closed form: sum 1/(D_{t-1} D_t) = (1/D_{t0-1} - 1/D_end)/c
        float Ds = fmaf(c, (float)(ch * ROWS) - 1.0f, v);
        float De = fmaf(c, (float)(ch * ROWS + ROWS - 1), v);
        float S0 = (1.0f / Ds - 1.0f / De) * invc;
        float cP = c * run;
        q += kq * (S2 - 2.f * cP * S1 + cP * cP * S0);
        run += s;
    }

    // block reduce (8 waves), subtract from out
    for (int off = 32; off > 0; off >>= 1) q += __shfl_down(q, off, 64);
    __shared__ float wsred[8];
    const int lane = d & 63, w = d >> 6;
    if (lane == 0) wsred[w] = q;
    __syncthreads();
    if (d == 0) {
        float tot = 0.f;
#pragma unroll
        for (int i = 0; i < 8; ++i) tot += wsred[i];
        atomicAdd(out, -tot);
    }
}

extern "C" void kernel_launch(void* const* d_in, const int* in_sizes, int n_in,
                              void* d_out, int out_size, void* d_ws, size_t ws_size,
                              hipStream_t stream) {
    const float* z = (const float*)d_in[0];
    const float* var_vbl = (const float*)d_in[1];
    const float* corr_vbl = (const float*)d_in[2];
    const float* prior_mu = (const float*)d_in[3];
    float* out = (float*)d_out;
    float* sums = (float*)d_ws;                          // CHUNKS*DIM (2 MB)
    float* s1a = sums + (size_t)CHUNKS * DIM;            // 2 MB
    float* s2a = s1a + (size_t)CHUNKS * DIM;             // 2 MB
    float* gsums = s2a + (size_t)CHUNKS * DIM;           // GROUPS*DIM (128 KB)

    k1_fused<<<CHUNKS, 128, 0, stream>>>(z, var_vbl, corr_vbl, prior_mu,
                                         sums, s1a, s2a);
    k2a_gsum<<<GROUPS + 1, 512, 0, stream>>>(sums, gsums, var_vbl, corr_vbl, out);
    k2b_combine<<<GROUPS, 512, 0, stream>>>(sums, s1a, s2a, gsums,
                                            var_vbl, corr_vbl, out);
}

// Round 12
// 209.588 us; speedup vs baseline: 1.1764x; 1.0007x over previous
//
#include <hip/hip_runtime.h>
#include <math.h>

// Problem: lkd scan over T=65536 steps, DIM=512, fp32. Closed form:
//   D_t = v + c*t ; mu_t = ((v-c)mu0 + c Z_t)/D_{t-1} ; Z_t excl. prefix of z.
//   Per-chunk moments: S1=sum r*w, S2=sum r*w^2 with r=1/(D_t D_{t-1}),
//   w = Dprev*z - k0 - c*L (L = excl. local prefix); chunk quadratic =
//   kq*(S2 - 2cP*S1 + (cP)^2*S0), P = inter-chunk excl. prefix.
//   S0 is data-independent: S0 = (1/D_{t0-1} - 1/D_end)/c (closed form in K2b).
//
// R6: K1 occupancy fix. R5 ran K1 at 1024 blocks x 128 thr = 8 waves/CU
// (2/SIMD) -> HBM latency-bound at ~4.5 TB/s. Now CHUNKS=2048 (ROWS=32)
// -> 16 waves/CU, unroll 8 -> >=8 independent float4 loads in flight/wave.
// K2b prefix uses 8 independent accumulators (no serial add chain; R4 lesson).
// Pipeline (3 dispatches, no memset):
//   K1 moments -> K2a group sums (+1 block fp64 logdet, plain-stores out)
//   -> K2b prefix+combine+atomicAdd.
// Workspace: 3*CHUNKS*DIM + GROUPS*DIM floats = 12.25 MB.

#define DIM    512
#define TT     65536
#define CHUNKS 2048
#define ROWS   32      // TT / CHUNKS
#define GROUPS 128
#define CPG    16      // CHUNKS / GROUPS

#define TWO_PI 6.283185307179586

// K1: fused colsum + moment pass. grid=CHUNKS, block=128 (4 cols/thread, float4).
__global__ __launch_bounds__(128) void k1_fused(const float* __restrict__ z,
                                                const float* __restrict__ var_vbl,
                                                const float* __restrict__ corr_vbl,
                                                const float* __restrict__ prior_mu,
                                                float* __restrict__ sums,
                                                float* __restrict__ s1a,
                                                float* __restrict__ s2a) {
    const int chunk = blockIdx.x;
    const int tid = threadIdx.x;  // 0..127
    const int d0 = tid * 4;
    const float t0m1 = (float)(chunk * ROWS) - 1.0f;

    float vv[4], cc[4], k0[4], L[4], S1[4], S2[4], Dprev[4], invDprev[4];
#pragma unroll
    for (int j = 0; j < 4; ++j) {
        const int d = d0 + j;
        float spv = log1pf(expf(var_vbl[d]));
        float v = spv * spv;
        float c = v / (1.0f + expf(-corr_vbl[d]));
        vv[j] = v;
        cc[j] = c;
        k0[j] = (v - c) * prior_mu[d];      // (v-c)*mu0
        L[j] = 0.f; S1[j] = 0.f; S2[j] = 0.f;
        Dprev[j] = fmaf(c, t0m1, v);        // D_{t0-1}
        invDprev[j] = __builtin_amdgcn_rcpf(Dprev[j]);
    }

    const float4* zp = reinterpret_cast<const float4*>(z)
                       + (size_t)chunk * ROWS * (DIM / 4) + tid;
    float tf = t0m1 + 1.0f;
#pragma unroll 8
    for (int r = 0; r < ROWS; ++r) {
        float4 zv = zp[(size_t)r * (DIM / 4)];
        float zz[4] = {zv.x, zv.y, zv.z, zv.w};
#pragma unroll
        for (int j = 0; j < 4; ++j) {
            float Dt = fmaf(cc[j], tf, vv[j]);             // v + c*t
            float invDt = __builtin_amdgcn_rcpf(Dt);
            float w = fmaf(Dprev[j], zz[j], -fmaf(cc[j], L[j], k0[j]));
            float rw = (invDt * invDprev[j]) * w;          // r_t * w
            S1[j] += rw;
            S2[j] = fmaf(rw, w, S2[j]);
            L[j] += zz[j];
            Dprev[j] = Dt;
            invDprev[j] = invDt;
        }
        tf += 1.0f;
    }

    const size_t o4 = (size_t)chunk * (DIM / 4) + tid;
    reinterpret_cast<float4*>(sums)[o4] = make_float4(L[0], L[1], L[2], L[3]);
    reinterpret_cast<float4*>(s1a)[o4] = make_float4(S1[0], S1[1], S1[2], S1[3]);
    reinterpret_cast<float4*>(s2a)[o4] = make_float4(S2[0], S2[1], S2[2], S2[3]);
}

// K2a: group totals (blocks 0..GROUPS-1) + fp64 logdet (block GROUPS).
// grid=GROUPS+1, block=512.
__global__ __launch_bounds__(512) void k2a_gsum(const float* __restrict__ sums,
                                                float* __restrict__ gsums,
                                                const float* __restrict__ var_vbl,
                                                const float* __restrict__ corr_vbl,
                                                float* __restrict__ out) {
    const int g = blockIdx.x;
    const int d = threadIdx.x;
    if (g < GROUPS) {
        float vals[CPG];
#pragma unroll
        for (int i = 0; i < CPG; ++i)
            vals[i] = sums[(size_t)(g * CPG + i) * DIM + d];
        float run = 0.f;
#pragma unroll
        for (int i = 0; i < CPG; ++i) run += vals[i];
        gsums[(size_t)g * DIM + d] = run;
    } else {
        // Analytic: sum_t -0.5*log(2pi var_t) telescopes. fp64 for accuracy.
        double sp = log1p(exp((double)var_vbl[d]));
        double vd = sp * sp;
        double cd = vd / (1.0 + exp(-(double)corr_vbl[d]));
        double vmc = vd - cd;
        double Dlast = vd + cd * (double)(TT - 1);
        double Ld = -0.5 * ((double)TT * (log(TWO_PI) + log(vmc)) + log(Dlast / vmc));
        __shared__ double redd[512];
        redd[d] = Ld;
        __syncthreads();
        for (int s = 256; s > 0; s >>= 1) {
            if (d < s) redd[d] += redd[d + s];
            __syncthreads();
        }
        if (d == 0) out[0] = (float)redd[0];   // plain store inits out
    }
}

// K2b: group-exclusive prefix (8 independent accumulators over <=127 rows)
// + combine CPG chunks + reduce. grid=GROUPS, block=512.
__global__ __launch_bounds__(512) void k2b_combine(const float* __restrict__ sums,
                                                   const float* __restrict__ s1a,
                                                   const float* __restrict__ s2a,
                                                   const float* __restrict__ gsums,
                                                   const float* __restrict__ var_vbl,
                                                   const float* __restrict__ corr_vbl,
                                                   float* __restrict__ out) {
    const int g = blockIdx.x;
    const int d = threadIdx.x;
    float spv = log1pf(expf(var_vbl[d]));
    float v = spv * spv;
    float c = v / (1.0f + expf(-corr_vbl[d]));
    float kq = 0.5f / (v - c);
    float invc = 1.0f / c;

    // Group-exclusive prefix: independent loads, 8 accumulators (no serial chain).
    float r0 = 0.f, r1 = 0.f, r2 = 0.f, r3 = 0.f;
    float r4 = 0.f, r5 = 0.f, r6 = 0.f, r7 = 0.f;
    int i = 0;
    for (; i + 8 <= g; i += 8) {
        r0 += gsums[(size_t)(i + 0) * DIM + d];
        r1 += gsums[(size_t)(i + 1) * DIM + d];
        r2 += gsums[(size_t)(i + 2) * DIM + d];
        r3 += gsums[(size_t)(i + 3) * DIM + d];
        r4 += gsums[(size_t)(i + 4) * DIM + d];
        r5 += gsums[(size_t)(i + 5) * DIM + d];
        r6 += gsums[(size_t)(i + 6) * DIM + d];
        r7 += gsums[(size_t)(i + 7) * DIM + d];
    }
    for (; i < g; ++i) r0 += gsums[(size_t)i * DIM + d];
    float run = ((r0 + r1) + (r2 + r3)) + ((r4 + r5) + (r6 + r7));

    float q = 0.f;
#pragma unroll
    for (int k = 0; k < CPG; ++k) {
        const int ch = g * CPG + k;
        const size_t idx = (size_t)ch * DIM + d;
        float s = sums[idx];
        float S1 = s1a[idx];
        float S2 = s2a[idx];
        // S0 closed form: sum 1/(D_{t-1} D_t) = (1/D_{t0-1} - 1/D_end)/c
        float Ds = fmaf(c, (float)(ch * ROWS) - 1.0f, v);
        float De = fmaf(c, (float)(ch * ROWS + ROWS - 1), v);
        float S0 = (1.0f / Ds - 1.0f / De) * invc;
        float cP = c * run;
        q += kq * (S2 - 2.f * cP * S1 + cP * cP * S0);
        run += s;
    }

    // block reduce (8 waves), subtract from out
    for (int off = 32; off > 0; off >>= 1) q += __shfl_down(q, off, 64);
    __shared__ float wsred[8];
    const int lane = d & 63, w = d >> 6;
    if (lane == 0) wsred[w] = q;
    __syncthreads();
    if (d == 0) {
        float tot = 0.f;
#pragma unroll
        for (int k = 0; k < 8; ++k) tot += wsred[k];
        atomicAdd(out, -tot);
    }
}

extern "C" void kernel_launch(void* const* d_in, const int* in_sizes, int n_in,
                              void* d_out, int out_size, void* d_ws, size_t ws_size,
                              hipStream_t stream) {
    const float* z = (const float*)d_in[0];
    const float* var_vbl = (const float*)d_in[1];
    const float* corr_vbl = (const float*)d_in[2];
    const float* prior_mu = (const float*)d_in[3];
    float* out = (float*)d_out;
    float* sums = (float*)d_ws;                          // CHUNKS*DIM (4 MB)
    float* s1a = sums + (size_t)CHUNKS * DIM;            // 4 MB
    float* s2a = s1a + (size_t)CHUNKS * DIM;             // 4 MB
    float* gsums = s2a + (size_t)CHUNKS * DIM;           // GROUPS*DIM (256 KB)

    k1_fused<<<CHUNKS, 128, 0, stream>>>(z, var_vbl, corr_vbl, prior_mu,
                                         sums, s1a, s2a);
    k2a_gsum<<<GROUPS + 1, 512, 0, stream>>>(sums, gsums, var_vbl, corr_vbl, out);
    k2b_combine<<<GROUPS, 512, 0, stream>>>(sums, s1a, s2a, gsums,
                                            var_vbl, corr_vbl, out);
}